// Round 8
// baseline (34.061 us; speedup 1.0000x reference)
//
#include <hip/hip_runtime.h>

// Batched GEMM formulation of AbsolutePosEmb:
//   per batch b,n (32 of them):
//     C[xy][pq] = sum_d Q[xy][d] * (K[pq][d] + ph[p][d] + pw[q][d])
//   M = N = 1024 (HW), K = 64 (D). Output f32, compute bf16 MFMA (f32 accum).
//
// Write-BW-bound: 134 MB output; pure-write ceiling ~6.87 TB/s.
//
// Round-8 (final structural probe):
//  - FULL-WIDTH STRIPS: each block owns 128 rows x 1024 cols of one batch
//    (grid 256 = 1/CU). A (Q) tile is only 32 KB f32 -> Q cold traffic
//    halves to 8.4 MB; staged-before-first-store drops 80->48 KB/block
//    (grid prologue burst 20.5 -> 12.3 MB, ~-1.2 us).
//  - A-fragments hoisted to registers once per block (4 x bf16x8 per wave);
//    the chunk loop reads only B from LDS.
//  - B staged in 16 x 64-col chunks (16 KB), double-buffered; per chunk:
//    prefetch c+1 -> 4 MFMA -> 16 stores (fire-and-forget) -> convert +
//    ds_write -> RAW BARRIER (s_waitcnt lgkmcnt(0) + s_barrier). The raw
//    barrier skips the compiler's vmcnt(0) store-queue drain that
//    __syncthreads() would emit -- stores stay in flight across all 15
//    inner barriers. LDS safety: each wave's ds ops complete at lgkmcnt(0)
//    before its barrier; double buffer gives write-after-read distance 2.
// Kept: chunked batch->XCD mapping, plain cached stores, LDSTRIDE=72.

typedef __bf16 bf16x8 __attribute__((ext_vector_type(8)));
typedef __bf16 bf16x4 __attribute__((ext_vector_type(4)));
typedef float  f32x16 __attribute__((ext_vector_type(16)));

#define LDSTRIDE 72   // bf16 elements per LDS row (64 data + 8 pad)

__global__ __launch_bounds__(512)
void abs_pos_emb_gemm(const float* __restrict__ q,
                      const float* __restrict__ k,
                      const float* __restrict__ ph,
                      const float* __restrict__ pw,
                      float* __restrict__ out)
{
    extern __shared__ __bf16 lds[];
    __bf16* As  = lds;                     // Q tile: 128 rows x 64 d
    __bf16* Bs0 = lds + 128 * LDSTRIDE;    // B chunk buffer 0: 64 x 64
    __bf16* Bs1 = lds + 192 * LDSTRIDE;    // B chunk buffer 1: 64 x 64

    const int tid = threadIdx.x;
    const int bid = blockIdx.x;            // [0,256)
    // chunked XCD mapping: XCD x = bid&7 runs batches 4x..4x+3 sequentially.
    const int batch = ((bid & 7) << 2) + (bid >> 6);
    const int j     = (bid >> 3) & 7;      // strip index in batch
    const int trow  = j << 7;              // 128-row band: 0,128,...,896

    const float* Qb = q + (size_t)batch * (1024 * 64);
    const float* Kb = k + (size_t)batch * (1024 * 64);
    float* Ob = out + (size_t)batch * (1024u * 1024u);

    // ---- stage A: Q tile (128x64) -> bf16 LDS ----
#pragma unroll
    for (int i = 0; i < 4; ++i) {
        int f   = i * 512 + tid;
        int row = f >> 4;
        int col = (f & 15) << 2;
        float4 v = *reinterpret_cast<const float4*>(
            Qb + (size_t)(trow + row) * 64 + col);
        bf16x4 h;
        h[0] = (__bf16)v.x; h[1] = (__bf16)v.y;
        h[2] = (__bf16)v.z; h[3] = (__bf16)v.w;
        *reinterpret_cast<bf16x4*>(&As[row * LDSTRIDE + col]) = h;
    }

    // ---- stage B chunk 0 (64 K-rows) ----
#pragma unroll
    for (int i = 0; i < 2; ++i) {
        int f   = i * 512 + tid;
        int row = f >> 4;                 // 0..63
        int col = (f & 15) << 2;
        int p  = row >> 5;
        int qq = row & 31;
        float4 v  = *reinterpret_cast<const float4*>(Kb + (size_t)row * 64 + col);
        float4 vp = *reinterpret_cast<const float4*>(ph + p  * 64 + col);
        float4 vw = *reinterpret_cast<const float4*>(pw + qq * 64 + col);
        bf16x4 h;
        h[0] = (__bf16)(v.x + vp.x + vw.x);
        h[1] = (__bf16)(v.y + vp.y + vw.y);
        h[2] = (__bf16)(v.z + vp.z + vw.z);
        h[3] = (__bf16)(v.w + vp.w + vw.w);
        *reinterpret_cast<bf16x4*>(&Bs0[row * LDSTRIDE + col]) = h;
    }

    __syncthreads();

    // ---- wave geometry: 8 waves in 4x2; per chunk each wave one 32x32 ----
    const int lane = tid & 63;
    const int wid  = tid >> 6;
    const int wrow = (wid >> 1) << 5;     // 0,32,64,96
    const int wcl  = (wid & 1)  << 5;     // 0,32 within 64-col chunk
    const int fr   = lane & 31;
    const int fk   = (lane >> 5) << 3;    // 0 or 8
    const int srow = trow + wrow + ((lane >> 5) << 2);

    // ---- hoist A-fragments to registers (loop-invariant across chunks) ----
    bf16x8 afrag[4];
#pragma unroll
    for (int kk = 0; kk < 4; ++kk) {
        afrag[kk] = *reinterpret_cast<const bf16x8*>(
            &As[(wrow + fr) * LDSTRIDE + kk * 16 + fk]);
    }

    // prefetch staging coordinates (fixed per thread)
    const int prow0 = tid >> 4;           // 0..31
    const int prow1 = prow0 + 32;         // 32..63
    const int pcol  = (tid & 15) << 2;

#pragma unroll
    for (int c = 0; c < 16; ++c) {
        const __bf16* B  = (c & 1) ? Bs1 : Bs0;
        __bf16*       Bn = (c & 1) ? Bs0 : Bs1;

        // ---- prefetch chunk c+1 into regs (before stores) ----
        float4 kv0, kv1, vp0, vp1, vw0, vw1;
        if (c < 15) {
            int g0 = (c + 1) * 64 + prow0;
            int g1 = (c + 1) * 64 + prow1;
            kv0 = *reinterpret_cast<const float4*>(Kb + (size_t)g0 * 64 + pcol);
            kv1 = *reinterpret_cast<const float4*>(Kb + (size_t)g1 * 64 + pcol);
            vp0 = *reinterpret_cast<const float4*>(ph + (g0 >> 5) * 64 + pcol);
            vp1 = *reinterpret_cast<const float4*>(ph + (g1 >> 5) * 64 + pcol);
            vw0 = *reinterpret_cast<const float4*>(pw + (g0 & 31) * 64 + pcol);
            vw1 = *reinterpret_cast<const float4*>(pw + (g1 & 31) * 64 + pcol);
        }

        // ---- MFMA chunk c: one 32x32 tile per wave, 4 k-steps ----
        f32x16 acc = {};
#pragma unroll
        for (int kk = 0; kk < 4; ++kk) {
            bf16x8 b0 = *reinterpret_cast<const bf16x8*>(
                &B[(wcl + fr) * LDSTRIDE + kk * 16 + fk]);
            acc = __builtin_amdgcn_mfma_f32_32x32x16_bf16(afrag[kk], b0, acc, 0, 0, 0);
        }

        // ---- store chunk c output (128 rows x 64 cols at c*64) ----
        {
            const int scol = (c << 6) + wcl + fr;
#pragma unroll
            for (int r = 0; r < 16; ++r) {
                int roff = (r & 3) + ((r >> 2) << 3);
                Ob[(size_t)(srow + roff) * 1024 + scol] = acc[r];
            }
        }

        // ---- convert + ds_write chunk c+1, then raw barrier (no vmcnt drain)
        if (c < 15) {
            bf16x4 h0, h1;
            h0[0] = (__bf16)(kv0.x + vp0.x + vw0.x);
            h0[1] = (__bf16)(kv0.y + vp0.y + vw0.y);
            h0[2] = (__bf16)(kv0.z + vp0.z + vw0.z);
            h0[3] = (__bf16)(kv0.w + vp0.w + vw0.w);
            h1[0] = (__bf16)(kv1.x + vp1.x + vw1.x);
            h1[1] = (__bf16)(kv1.y + vp1.y + vw1.y);
            h1[2] = (__bf16)(kv1.z + vp1.z + vw1.z);
            h1[3] = (__bf16)(kv1.w + vp1.w + vw1.w);
            *reinterpret_cast<bf16x4*>(&Bn[prow0 * LDSTRIDE + pcol]) = h0;
            *reinterpret_cast<bf16x4*>(&Bn[prow1 * LDSTRIDE + pcol]) = h1;
            // all of this wave's ds ops (reads of B, writes of Bn) complete:
            asm volatile("s_waitcnt lgkmcnt(0)" ::: "memory");
            __builtin_amdgcn_s_barrier();
        }
    }
}

extern "C" void kernel_launch(void* const* d_in, const int* in_sizes, int n_in,
                              void* d_out, int out_size, void* d_ws, size_t ws_size,
                              hipStream_t stream) {
    const float* q  = (const float*)d_in[0];
    const float* k  = (const float*)d_in[1];
    const float* ph = (const float*)d_in[2];
    const float* pw = (const float*)d_in[3];
    float* out = (float*)d_out;

    // 32 batches * 8 strips (128 rows x 1024 cols) = 256 blocks, 512 threads.
    // dynamic LDS: A 128 rows + 2 B-chunk buffers (64 rows each), stride 72:
    // (128 + 128) * 72 * 2 B = 36864 B
    size_t lds_bytes = (128u + 128u) * LDSTRIDE * sizeof(__bf16);
    hipLaunchKernelGGL(abs_pos_emb_gemm, dim3(256), dim3(512), lds_bytes, stream,
                       q, k, ph, pw, out);
}

// Round 9
// 28.641 us; speedup vs baseline: 1.1892x; 1.1892x over previous
//
#include <hip/hip_runtime.h>

// Batched GEMM formulation of AbsolutePosEmb:
//   per batch b,n (32 of them):
//     C[xy][pq] = sum_d Q[xy][d] * (K[pq][d] + ph[p][d] + pw[q][d])
//   M = N = 1024 (HW), K = 64 (D). Output f32, compute bf16 MFMA (f32 accum).
//
// Write-BW-bound: 134 MB output; pure-write ceiling ~6.87 TB/s -> ~22-23 us
// floor incl. cold reads.
//
// ROUND 9 = EXACT REVERT TO ROUND 7 (best: 28.7 us). Round 8's bundle
// (full-width strips + raw barrier) regressed to 34.1 us:
//  - full-width strips doubled K load traffic (every block read the whole
//    K batch) and halved per-barrier MFMA work while doubling barrier count;
//  - the raw-barrier vmcnt trick was void: the convert's load-wait is a FIFO
//    vmcnt wait, which forces prior iterations' stores to drain anyway.
//
// Structure (round 7): each block owns a 256x512 output strip of one batch.
// B (K+emb) staged in EIGHT 64-row chunks (16 KB), double-buffered:
//   prefetch c+1 (regs, issued before stores) -> 8 MFMA -> 32 stores
//   (fire-and-forget) -> convert+ds_write -> __syncthreads.
// A (Q) staged once (64 KB) and reused by all 8 chunks.
// Kept: chunked batch->XCD mapping (XCD x runs batches 4x..4x+3
// sequentially; hot set 512 KB/XCD), plain cached stores, LDSTRIDE=72.

typedef __bf16 bf16x8 __attribute__((ext_vector_type(8)));
typedef __bf16 bf16x4 __attribute__((ext_vector_type(4)));
typedef float  f32x16 __attribute__((ext_vector_type(16)));

#define LDSTRIDE 72   // bf16 elements per LDS row (64 data + 8 pad)

__global__ __launch_bounds__(512)
void abs_pos_emb_gemm(const float* __restrict__ q,
                      const float* __restrict__ k,
                      const float* __restrict__ ph,
                      const float* __restrict__ pw,
                      float* __restrict__ out)
{
    extern __shared__ __bf16 lds[];
    __bf16* As  = lds;                     // Q tile: 256 rows x 64 d
    __bf16* Bs0 = lds + 256 * LDSTRIDE;    // B chunk buffer 0: 64 x 64
    __bf16* Bs1 = lds + 320 * LDSTRIDE;    // B chunk buffer 1: 64 x 64

    const int tid = threadIdx.x;
    const int bid = blockIdx.x;            // [0,256)
    // chunked XCD mapping: XCD x = bid&7 runs batches 4x..4x+3 sequentially.
    const int batch = ((bid & 7) << 2) + (bid >> 6);
    const int j     = (bid >> 3) & 7;      // strip index in batch
    const int trow  = (j >> 1) << 8;       // row band: 0,256,512,768
    const int tcol0 = (j & 1) << 9;        // col half: 0 or 512 (strip = 512 wide)

    const float* Qb = q + (size_t)batch * (1024 * 64);
    const float* Kb = k + (size_t)batch * (1024 * 64);
    float* Ob = out + (size_t)batch * (1024u * 1024u);

    // ---- stage A: Q tile (256x64) -> bf16 LDS ----
#pragma unroll
    for (int i = 0; i < 8; ++i) {
        int f   = i * 512 + tid;
        int row = f >> 4;
        int col = (f & 15) << 2;
        float4 v = *reinterpret_cast<const float4*>(
            Qb + (size_t)(trow + row) * 64 + col);
        bf16x4 h;
        h[0] = (__bf16)v.x; h[1] = (__bf16)v.y;
        h[2] = (__bf16)v.z; h[3] = (__bf16)v.w;
        *reinterpret_cast<bf16x4*>(&As[row * LDSTRIDE + col]) = h;
    }

    // ---- stage B chunk 0 (64 rows) ----
#pragma unroll
    for (int i = 0; i < 2; ++i) {
        int f   = i * 512 + tid;
        int row = f >> 4;                 // 0..63
        int col = (f & 15) << 2;
        int grow = tcol0 + row;
        int p  = grow >> 5;
        int qq = grow & 31;
        float4 v  = *reinterpret_cast<const float4*>(Kb + (size_t)grow * 64 + col);
        float4 vp = *reinterpret_cast<const float4*>(ph + p  * 64 + col);
        float4 vw = *reinterpret_cast<const float4*>(pw + qq * 64 + col);
        bf16x4 h;
        h[0] = (__bf16)(v.x + vp.x + vw.x);
        h[1] = (__bf16)(v.y + vp.y + vw.y);
        h[2] = (__bf16)(v.z + vp.z + vw.z);
        h[3] = (__bf16)(v.w + vp.w + vw.w);
        *reinterpret_cast<bf16x4*>(&Bs0[row * LDSTRIDE + col]) = h;
    }

    __syncthreads();

    // ---- wave geometry: 8 waves, 4x2 grid; per chunk each wave does 64x32 ----
    const int lane = tid & 63;
    const int wid  = tid >> 6;
    const int wrow = (wid >> 1) << 6;     // 0,64,128,192
    const int wcl  = (wid & 1)  << 5;     // 0,32 (within 64-col chunk)
    const int fr   = lane & 31;
    const int fk   = (lane >> 5) << 3;
    const int srow = trow + wrow + ((lane >> 5) << 2);

    // prefetch staging coordinates (fixed per thread)
    const int prow0 = tid >> 4;           // 0..31
    const int prow1 = prow0 + 32;         // 32..63
    const int pcol  = (tid & 15) << 2;

#pragma unroll
    for (int c = 0; c < 8; ++c) {
        const __bf16* B  = (c & 1) ? Bs1 : Bs0;
        __bf16*       Bn = (c & 1) ? Bs0 : Bs1;

        // ---- prefetch chunk c+1 into regs (before stores -> no queue drain)
        float4 kv0, kv1, vp0, vp1, vw0, vw1;
        if (c < 7) {
            int g0 = tcol0 + (c + 1) * 64 + prow0;
            int g1 = tcol0 + (c + 1) * 64 + prow1;
            kv0 = *reinterpret_cast<const float4*>(Kb + (size_t)g0 * 64 + pcol);
            kv1 = *reinterpret_cast<const float4*>(Kb + (size_t)g1 * 64 + pcol);
            vp0 = *reinterpret_cast<const float4*>(ph + (g0 >> 5) * 64 + pcol);
            vp1 = *reinterpret_cast<const float4*>(ph + (g1 >> 5) * 64 + pcol);
            vw0 = *reinterpret_cast<const float4*>(pw + (g0 & 31) * 64 + pcol);
            vw1 = *reinterpret_cast<const float4*>(pw + (g1 & 31) * 64 + pcol);
        }

        // ---- MFMA chunk c ----
        f32x16 acc0 = {};
        f32x16 acc1 = {};
#pragma unroll
        for (int kk = 0; kk < 4; ++kk) {
            const int kb = kk * 16 + fk;
            bf16x8 a0 = *reinterpret_cast<const bf16x8*>(&As[(wrow      + fr) * LDSTRIDE + kb]);
            bf16x8 a1 = *reinterpret_cast<const bf16x8*>(&As[(wrow + 32 + fr) * LDSTRIDE + kb]);
            bf16x8 b0 = *reinterpret_cast<const bf16x8*>(&B [(wcl       + fr) * LDSTRIDE + kb]);
            acc0 = __builtin_amdgcn_mfma_f32_32x32x16_bf16(a0, b0, acc0, 0, 0, 0);
            acc1 = __builtin_amdgcn_mfma_f32_32x32x16_bf16(a1, b0, acc1, 0, 0, 0);
        }

        // ---- store chunk c output (256 x 64 cols at tcol0 + c*64) ----
        {
            const int scol = tcol0 + (c << 6) + wcl + fr;
#pragma unroll
            for (int r = 0; r < 16; ++r) {
                int roff = (r & 3) + ((r >> 2) << 3);
                Ob[(size_t)(srow + roff) * 1024 + scol]      = acc0[r];
            }
#pragma unroll
            for (int r = 0; r < 16; ++r) {
                int roff = (r & 3) + ((r >> 2) << 3);
                Ob[(size_t)(srow + 32 + roff) * 1024 + scol] = acc1[r];
            }
        }

        // ---- convert + ds_write chunk c+1, then barrier ----
        if (c < 7) {
            bf16x4 h0, h1;
            h0[0] = (__bf16)(kv0.x + vp0.x + vw0.x);
            h0[1] = (__bf16)(kv0.y + vp0.y + vw0.y);
            h0[2] = (__bf16)(kv0.z + vp0.z + vw0.z);
            h0[3] = (__bf16)(kv0.w + vp0.w + vw0.w);
            h1[0] = (__bf16)(kv1.x + vp1.x + vw1.x);
            h1[1] = (__bf16)(kv1.y + vp1.y + vw1.y);
            h1[2] = (__bf16)(kv1.z + vp1.z + vw1.z);
            h1[3] = (__bf16)(kv1.w + vp1.w + vw1.w);
            *reinterpret_cast<bf16x4*>(&Bn[prow0 * LDSTRIDE + pcol]) = h0;
            *reinterpret_cast<bf16x4*>(&Bn[prow1 * LDSTRIDE + pcol]) = h1;
            __syncthreads();
        }
    }
}

extern "C" void kernel_launch(void* const* d_in, const int* in_sizes, int n_in,
                              void* d_out, int out_size, void* d_ws, size_t ws_size,
                              hipStream_t stream) {
    const float* q  = (const float*)d_in[0];
    const float* k  = (const float*)d_in[1];
    const float* ph = (const float*)d_in[2];
    const float* pw = (const float*)d_in[3];
    float* out = (float*)d_out;

    // 32 batches * 8 strips (256 rows x 512 cols) = 256 blocks, 512 threads.
    // dynamic LDS: A 256 rows + 2 B-chunk buffers (64 rows each), stride 72:
    // (256 + 128) * 72 * 2 B = 55296 B
    size_t lds_bytes = (256u + 128u) * LDSTRIDE * sizeof(__bf16);
    hipLaunchKernelGGL(abs_pos_emb_gemm, dim3(256), dim3(512), lds_bytes, stream,
                       q, k, ph, pw, out);
}